// Round 9
// baseline (1704.256 us; speedup 1.0000x reference)
//
#include <hip/hip_runtime.h>
#include <math.h>

#define TT 2048
#define UU 64
#define BB 256
#define NW 5             // 4 producer waves (k-quarters) + 1 layer-1 consumer
#define NTHR (NW * 64)

// Fast activations on v_exp_f32 / v_rcp_f32 (validated absmax 9.5e-7, thr 3.45e-6).
__device__ __forceinline__ float frcp(float x) { return __builtin_amdgcn_rcpf(x); }
__device__ __forceinline__ float fsigmoid(float x) { return frcp(1.0f + __expf(-x)); }
__device__ __forceinline__ float ftanh(float x) { return 1.0f - 2.0f * frcp(1.0f + __expf(2.0f * x)); }

// R8 lesson: v_fmac_f32 cannot take an AGPR in vsrc1 (8-bit VGPR-only field) —
// AGPRs are NOT general VALU sources on gfx950; v_accvgpr_read is the only
// path (2 instr/MAC floor). R9 = R8's structure with the R7-proven access:
//  - 4 producer waves: wave q owns k in [16q,16q+16), lane u owns ALL 4 gate
//    columns of unit u -> 16 readlanes/wave (each reused x4), activation
//    redundancy 4x (exactly 1 producer wave per SIMD).
//  - 64 weights/lane in AGPR stash; asm VOLATILE v_accvgpr_read per use
//    (volatile prevents loop-invariant hoisting -> would recreate the spill).
//  - zp[buf][gate][q][64]: stride-1 per lane both directions, conflict-free.
// ONE barrier/step; redundant unit update keeps h register-resident for the
// readlane broadcast; consumer wave = proven lagged layer-1 + coalesced store.
__global__ __launch_bounds__(NTHR, 1)
void lstm_ts_kernel(
    const float* __restrict__ x, const float* __restrict__ W0,
    const float* __restrict__ b0, const float* __restrict__ W1,
    const float* __restrict__ b1, const float* __restrict__ Wd,
    const float* __restrict__ bd, float* __restrict__ out)
{
    __shared__ float xbuf[TT];
    __shared__ float zp[2][4][4][UU];   // [buf][gate][q][u]
    __shared__ float ring[2][UU];
    __shared__ float red[NW];

    const int tid = threadIdx.x;
    const int wid = tid >> 6;
    const int u = tid & 63;
    const int b = blockIdx.x;
    const float* xrow = x + b * TT;
    float* outrow = out + b * TT;

    // ---- prologue: stage x, sum of squares over T ----
    float ss = 0.f;
    for (int i = tid; i < TT; i += NTHR) {
        float v = xrow[i];
        xbuf[i] = v;
        ss += v * v;
    }
    #pragma unroll
    for (int m = 1; m < 64; m <<= 1) ss += __shfl_xor(ss, m, 64);
    if (u == 0) red[wid] = ss;
    __syncthreads();  // B_pro

    if (wid < 4) {
        // ============ PRODUCER wave q: k in [16q, 16q+16) ============
        const int q = wid;

        float sq = 0.f;
        #pragma unroll
        for (int i = 0; i < NW; ++i) sq += red[i];
        const float scale = 1.0f / sqrtf(fmaxf(sq, 1e-12f));  // precise, once

        // ---- 64 weights (16 k x 4 gates) -> AGPR stash ----
        // ag{j}_{g} = W0[(1 + 16q + j)*256 + g*64 + u]
        #define DECLW(j) float ag##j##_0, ag##j##_1, ag##j##_2, ag##j##_3; { \
            const int r_ = (1 + 16 * q + j) * 256 + u; \
            float t0_ = W0[r_], t1_ = W0[r_ + 64], t2_ = W0[r_ + 128], t3_ = W0[r_ + 192]; \
            asm volatile("v_accvgpr_write_b32 %0, %1" : "=a"(ag##j##_0) : "v"(t0_)); \
            asm volatile("v_accvgpr_write_b32 %0, %1" : "=a"(ag##j##_1) : "v"(t1_)); \
            asm volatile("v_accvgpr_write_b32 %0, %1" : "=a"(ag##j##_2) : "v"(t2_)); \
            asm volatile("v_accvgpr_write_b32 %0, %1" : "=a"(ag##j##_3) : "v"(t3_)); }
        DECLW(0)  DECLW(1)  DECLW(2)  DECLW(3)
        DECLW(4)  DECLW(5)  DECLW(6)  DECLW(7)
        DECLW(8)  DECLW(9)  DECLW(10) DECLW(11)
        DECLW(12) DECLW(13) DECLW(14) DECLW(15)
        #undef DECLW

        // x-weight + bias folded into the q==0 partial only (zeros elsewhere)
        const float wxs0 = (q == 0) ? W0[u] * scale        : 0.f;
        const float wxs1 = (q == 0) ? W0[64 + u] * scale   : 0.f;
        const float wxs2 = (q == 0) ? W0[128 + u] * scale  : 0.f;
        const float wxs3 = (q == 0) ? W0[192 + u] * scale  : 0.f;
        const float bc0 = (q == 0) ? b0[u] : 0.f;
        const float bc1 = (q == 0) ? b0[64 + u] : 0.f;
        const float bc2 = (q == 0) ? b0[128 + u] : 0.f;
        const float bc3 = (q == 0) ? b0[192 + u] : 0.f;

        float c0 = 0.f, h = 0.f;

        for (int t = 0; t < TT; ++t) {
            const int p = t & 1;
            const int hi = __float_as_int(h);
            const float xr = xbuf[t];

            // ---- partial matvec: 16 readlane (reused x4), 64 (read+fmac) ----
            float z0 = fmaf(xr, wxs0, bc0);
            float z1 = fmaf(xr, wxs1, bc1);
            float z2 = fmaf(xr, wxs2, bc2);
            float z3 = fmaf(xr, wxs3, bc3);
            #define MACJ(j) { \
                const float hk_ = __int_as_float(__builtin_amdgcn_readlane(hi, 16 * q + j)); \
                float w0_, w1_, w2_, w3_; \
                asm volatile("v_accvgpr_read_b32 %0, %1" : "=v"(w0_) : "a"(ag##j##_0)); \
                asm volatile("v_accvgpr_read_b32 %0, %1" : "=v"(w1_) : "a"(ag##j##_1)); \
                asm volatile("v_accvgpr_read_b32 %0, %1" : "=v"(w2_) : "a"(ag##j##_2)); \
                asm volatile("v_accvgpr_read_b32 %0, %1" : "=v"(w3_) : "a"(ag##j##_3)); \
                z0 = fmaf(hk_, w0_, z0); \
                z1 = fmaf(hk_, w1_, z1); \
                z2 = fmaf(hk_, w2_, z2); \
                z3 = fmaf(hk_, w3_, z3); }
            MACJ(0)  MACJ(1)  MACJ(2)  MACJ(3)
            MACJ(4)  MACJ(5)  MACJ(6)  MACJ(7)
            MACJ(8)  MACJ(9)  MACJ(10) MACJ(11)
            MACJ(12) MACJ(13) MACJ(14) MACJ(15)
            #undef MACJ

            zp[p][0][q][u] = z0;
            zp[p][1][q][u] = z1;
            zp[p][2][q][u] = z2;
            zp[p][3][q][u] = z3;
            __syncthreads();  // B(t)

            // ---- redundant unit update (all 4 waves; keeps h in registers) ----
            const float zi = (zp[p][0][0][u] + zp[p][0][1][u]) + (zp[p][0][2][u] + zp[p][0][3][u]);
            const float zj = (zp[p][1][0][u] + zp[p][1][1][u]) + (zp[p][1][2][u] + zp[p][1][3][u]);
            const float zf = (zp[p][2][0][u] + zp[p][2][1][u]) + (zp[p][2][2][u] + zp[p][2][3][u]);
            const float zo = (zp[p][3][0][u] + zp[p][3][1][u]) + (zp[p][3][2][u] + zp[p][3][3][u]);
            c0 = fsigmoid(zf + 1.0f) * c0 + fsigmoid(zi) * ftanh(zj);
            h = fsigmoid(zo) * ftanh(c0);
            if (q == 0) ring[p][u] = h;  // publish h(t) for the consumer
        }
        __syncthreads();  // B_epi
    } else {
        // ================= CONSUMER: layer 1 + dense + store =================
        const float w1v0 = W1[u * 4 + 0], w1v1 = W1[u * 4 + 1];
        const float w1v2 = W1[u * 4 + 2], w1v3 = W1[u * 4 + 3];
        const float w1h0 = W1[256], w1h1 = W1[257], w1h2 = W1[258], w1h3 = W1[259];
        const float b10 = b1[0], b11 = b1[1], b12 = b1[2], b13 = b1[3];
        const float wd = Wd[0], bdv = bd[0];

        float c1 = 0.f, h1 = 0.f, oval = 0.f;

        #define L1STEP(s) { \
            const float hu = ring[(s) & 1][u]; \
            float p0 = hu * w1v0, p1 = hu * w1v1, p2 = hu * w1v2, p3 = hu * w1v3; \
            _Pragma("unroll") \
            for (int m = 1; m < 64; m <<= 1) { \
                p0 += __shfl_xor(p0, m, 64); \
                p1 += __shfl_xor(p1, m, 64); \
                p2 += __shfl_xor(p2, m, 64); \
                p3 += __shfl_xor(p3, m, 64); \
            } \
            const float z1i = p0 + fmaf(h1, w1h0, b10); \
            const float z1j = p1 + fmaf(h1, w1h1, b11); \
            const float z1f = p2 + fmaf(h1, w1h2, b12); \
            const float z1o = p3 + fmaf(h1, w1h3, b13); \
            c1 = fsigmoid(z1f + 1.0f) * c1 + fsigmoid(z1i) * ftanh(z1j); \
            h1 = fsigmoid(z1o) * ftanh(c1); \
            const float ov = fmaf(h1, wd, bdv); \
            if (((s) & 63) == u) oval = ov; \
            if (((s) & 63) == 63) outrow[((s) & ~63) + u] = oval; \
        }

        for (int t = 0; t < TT; ++t) {
            __syncthreads();  // B(t)
            if (t > 0) L1STEP(t - 1)   // ring[(t-1)&1] written before B(t)
        }
        __syncthreads();  // B_epi — makes ring[(TT-1)&1] visible
        L1STEP(TT - 1)
        #undef L1STEP
    }
}

extern "C" void kernel_launch(void* const* d_in, const int* in_sizes, int n_in,
                              void* d_out, int out_size, void* d_ws, size_t ws_size,
                              hipStream_t stream) {
    const float* x  = (const float*)d_in[0];
    const float* W0 = (const float*)d_in[1];
    const float* b0 = (const float*)d_in[2];
    const float* W1 = (const float*)d_in[3];
    const float* b1 = (const float*)d_in[4];
    const float* Wd = (const float*)d_in[5];
    const float* bd = (const float*)d_in[6];
    float* out = (float*)d_out;
    lstm_ts_kernel<<<BB, NTHR, 0, stream>>>(x, W0, b0, W1, b1, Wd, bd, out);
}

// Round 10
// 1671.581 us; speedup vs baseline: 1.0195x; 1.0195x over previous
//
#include <hip/hip_runtime.h>
#include <math.h>

#define TT 2048
#define UU 64
#define BB 256
#define NW 9             // 8 producer waves (2 gate-pairs x 4 k-quarters) + 1 consumer
#define NTHR (NW * 64)

// Fast activations on v_exp_f32 / v_rcp_f32 (validated absmax 9.5e-7, thr 3.45e-6).
__device__ __forceinline__ float frcp(float x) { return __builtin_amdgcn_rcpf(x); }
__device__ __forceinline__ float fsigmoid(float x) { return frcp(1.0f + __expf(-x)); }
__device__ __forceinline__ float ftanh(float x) { return 1.0f - 2.0f * frcp(1.0f + __expf(2.0f * x)); }

// Round matrix: R5(5w,spill)=1269, R7(9w,AGPR)=1280, R9(5w,AGPR)=1704 -> wave
// count dominates (latency hiding); 9 waves is the proven shape. R10 keeps it
// and cuts matvec instructions 96->80 per producer wave: wave (gp,q) lane u
// owns TWO gate columns {2gp*64+u,(2gp+1)*64+u} over k in [16q,16q+16), so
// each readlane feeds 2 fmacs: 16 readlane + 32 accvgpr_read + 32 fmac.
// Weights in the R7-proven AGPR stash (volatile v_accvgpr_read per use;
// non-volatile would hoist -> 64 live VGPRs -> spill returns). z-partials in
// zq[buf][q][gate][unit]: stride-1 in u both directions (conflict-free);
// gather = 16 b32 broadcast-pair reads. ONE barrier/step; redundant unit
// update in all 8 producer waves keeps h register-resident for readlane.
// Consumer wave = proven lagged layer-1 + dense + coalesced stores.
__global__ __launch_bounds__(NTHR, 1)
void lstm_ts_kernel(
    const float* __restrict__ x, const float* __restrict__ W0,
    const float* __restrict__ b0, const float* __restrict__ W1,
    const float* __restrict__ b1, const float* __restrict__ Wd,
    const float* __restrict__ bd, float* __restrict__ out)
{
    __shared__ float xbuf[TT];
    __shared__ float zq[2][4][4][UU];   // [buf][q][gate][u]
    __shared__ float ring[2][UU];
    __shared__ float red[NW];

    const int tid = threadIdx.x;
    const int wid = tid >> 6;
    const int u = tid & 63;
    const int b = blockIdx.x;
    const float* xrow = x + b * TT;
    float* outrow = out + b * TT;

    // ---- prologue: stage x, sum of squares over T ----
    float ss = 0.f;
    for (int i = tid; i < TT; i += NTHR) {
        float v = xrow[i];
        xbuf[i] = v;
        ss += v * v;
    }
    #pragma unroll
    for (int m = 1; m < 64; m <<= 1) ss += __shfl_xor(ss, m, 64);
    if (u == 0) red[wid] = ss;
    __syncthreads();  // B_pro

    if (wid < 8) {
        // ========= PRODUCER wave (gp, q): gates {2gp,2gp+1}, k in [16q,16q+16) =========
        const int gp = wid >> 2;
        const int q  = wid & 3;
        const int cA = (2 * gp) * 64 + u;
        const int cB = (2 * gp + 1) * 64 + u;

        float sq = 0.f;
        #pragma unroll
        for (int i = 0; i < NW; ++i) sq += red[i];
        const float scale = 1.0f / sqrtf(fmaxf(sq, 1e-12f));  // precise, once

        // ---- 32 weights (16 k x 2 cols) -> AGPR stash ----
        #define DECLW(j) float agA##j, agB##j; { \
            const int r_ = (1 + 16 * q + j) * 256; \
            float tA_ = W0[r_ + cA], tB_ = W0[r_ + cB]; \
            asm volatile("v_accvgpr_write_b32 %0, %1" : "=a"(agA##j) : "v"(tA_)); \
            asm volatile("v_accvgpr_write_b32 %0, %1" : "=a"(agB##j) : "v"(tB_)); }
        DECLW(0)  DECLW(1)  DECLW(2)  DECLW(3)
        DECLW(4)  DECLW(5)  DECLW(6)  DECLW(7)
        DECLW(8)  DECLW(9)  DECLW(10) DECLW(11)
        DECLW(12) DECLW(13) DECLW(14) DECLW(15)
        #undef DECLW

        // x-weight + bias folded into the q==0 partial only (zeros elsewhere)
        const float wxsA = (q == 0) ? W0[cA] * scale : 0.f;
        const float wxsB = (q == 0) ? W0[cB] * scale : 0.f;
        const float bcA  = (q == 0) ? b0[cA] : 0.f;
        const float bcB  = (q == 0) ? b0[cB] : 0.f;

        float c0 = 0.f, h = 0.f;

        for (int t = 0; t < TT; ++t) {
            const int p = t & 1;
            const int hi = __float_as_int(h);
            const float xr = xbuf[t];

            // ---- partial matvec: 16 readlane (each reused x2), 32 (read+fmac) ----
            float zA = fmaf(xr, wxsA, bcA);
            float zB = fmaf(xr, wxsB, bcB);
            #define MACJ(j) { \
                const float hk_ = __int_as_float(__builtin_amdgcn_readlane(hi, 16 * q + j)); \
                float wA_, wB_; \
                asm volatile("v_accvgpr_read_b32 %0, %1" : "=v"(wA_) : "a"(agA##j)); \
                asm volatile("v_accvgpr_read_b32 %0, %1" : "=v"(wB_) : "a"(agB##j)); \
                zA = fmaf(hk_, wA_, zA); \
                zB = fmaf(hk_, wB_, zB); }
            MACJ(0)  MACJ(1)  MACJ(2)  MACJ(3)
            MACJ(4)  MACJ(5)  MACJ(6)  MACJ(7)
            MACJ(8)  MACJ(9)  MACJ(10) MACJ(11)
            MACJ(12) MACJ(13) MACJ(14) MACJ(15)
            #undef MACJ

            zq[p][q][2 * gp][u]     = zA;
            zq[p][q][2 * gp + 1][u] = zB;
            __syncthreads();  // B(t)

            // ---- redundant unit update (all 8 waves; keeps h in registers) ----
            const float zi = (zq[p][0][0][u] + zq[p][1][0][u]) + (zq[p][2][0][u] + zq[p][3][0][u]);
            const float zj = (zq[p][0][1][u] + zq[p][1][1][u]) + (zq[p][2][1][u] + zq[p][3][1][u]);
            const float zf = (zq[p][0][2][u] + zq[p][1][2][u]) + (zq[p][2][2][u] + zq[p][3][2][u]);
            const float zo = (zq[p][0][3][u] + zq[p][1][3][u]) + (zq[p][2][3][u] + zq[p][3][3][u]);
            c0 = fsigmoid(zf + 1.0f) * c0 + fsigmoid(zi) * ftanh(zj);
            h = fsigmoid(zo) * ftanh(c0);
            if (wid == 0) ring[p][u] = h;  // publish h(t) for the consumer
        }
        __syncthreads();  // B_epi
    } else {
        // ================= CONSUMER: layer 1 + dense + store =================
        const float w1v0 = W1[u * 4 + 0], w1v1 = W1[u * 4 + 1];
        const float w1v2 = W1[u * 4 + 2], w1v3 = W1[u * 4 + 3];
        const float w1h0 = W1[256], w1h1 = W1[257], w1h2 = W1[258], w1h3 = W1[259];
        const float b10 = b1[0], b11 = b1[1], b12 = b1[2], b13 = b1[3];
        const float wd = Wd[0], bdv = bd[0];

        float c1 = 0.f, h1 = 0.f, oval = 0.f;

        #define L1STEP(s) { \
            const float hu = ring[(s) & 1][u]; \
            float p0 = hu * w1v0, p1 = hu * w1v1, p2 = hu * w1v2, p3 = hu * w1v3; \
            _Pragma("unroll") \
            for (int m = 1; m < 64; m <<= 1) { \
                p0 += __shfl_xor(p0, m, 64); \
                p1 += __shfl_xor(p1, m, 64); \
                p2 += __shfl_xor(p2, m, 64); \
                p3 += __shfl_xor(p3, m, 64); \
            } \
            const float z1i = p0 + fmaf(h1, w1h0, b10); \
            const float z1j = p1 + fmaf(h1, w1h1, b11); \
            const float z1f = p2 + fmaf(h1, w1h2, b12); \
            const float z1o = p3 + fmaf(h1, w1h3, b13); \
            c1 = fsigmoid(z1f + 1.0f) * c1 + fsigmoid(z1i) * ftanh(z1j); \
            h1 = fsigmoid(z1o) * ftanh(c1); \
            const float ov = fmaf(h1, wd, bdv); \
            if (((s) & 63) == u) oval = ov; \
            if (((s) & 63) == 63) outrow[((s) & ~63) + u] = oval; \
        }

        for (int t = 0; t < TT; ++t) {
            __syncthreads();  // B(t)
            if (t > 0) L1STEP(t - 1)   // ring[(t-1)&1] written before B(t)
        }
        __syncthreads();  // B_epi — makes ring[(TT-1)&1] visible
        L1STEP(TT - 1)
        #undef L1STEP
    }
}

extern "C" void kernel_launch(void* const* d_in, const int* in_sizes, int n_in,
                              void* d_out, int out_size, void* d_ws, size_t ws_size,
                              hipStream_t stream) {
    const float* x  = (const float*)d_in[0];
    const float* W0 = (const float*)d_in[1];
    const float* b0 = (const float*)d_in[2];
    const float* W1 = (const float*)d_in[3];
    const float* b1 = (const float*)d_in[4];
    const float* Wd = (const float*)d_in[5];
    const float* bd = (const float*)d_in[6];
    float* out = (float*)d_out;
    lstm_ts_kernel<<<BB, NTHR, 0, stream>>>(x, W0, b0, W1, b1, Wd, bd, out);
}